// Round 12
// baseline (295.115 us; speedup 1.0000x reference)
//
#include <hip/hip_runtime.h>
#include <hip/hip_fp16.h>
#include <math.h>

typedef unsigned long long u64;
typedef __attribute__((ext_vector_type(2))) _Float16 half2v;
typedef __attribute__((ext_vector_type(4))) _Float16 half4v;
typedef __attribute__((ext_vector_type(8))) _Float16 half8;
typedef __attribute__((ext_vector_type(4))) float f32x4;
typedef __attribute__((ext_vector_type(2))) float f32x2;

// ============================================================================
// v18 = v17 (292.4us, best) + k_build 4-way replicated LDS counters:
//  - k_build was the never-measured whale: 196 blocks (single round, duration
//    = per-block latency), each doing 2 x ~8163 LDS atomics onto 256 counters
//    (~32 collisions/addr) in count + scatter passes. Replicate stat/fill x4
//    (quadrant t>>8 owns copy) -> 4x less same-address serialization in BOTH
//    passes. Per-copy scatter bases compose exactly (quadrant scatters the
//    records it counted). stat4 unions with lcsr (dead before lcsr written).
// v17: pool fence fix (per-wave __threadfence = full-L2 writeback was the
//   50-80us pool floor; release = s_waitcnt vmcnt(0), acquire fence only in
//   last-done block).
// v16: pool 16 nodes/wave + block-LDS group slots. v15: k_build single-pass
//   reg-cached queue, hbuf fp16, single memset. v14: attn depth-1 pipeline.
// v13 PM: global-atomic scatter 15x write amp -> REVERTED.
// v12: 256-dst buckets + attn diet. v10: DPP butterfly. v7: MFMA transforms.
// Queue record u64: [48:25]=attr fixed-24, [24:17]=dst&255, [16:0]=src.
// csr record u32: [31:17]=fp16-attr-bits>>1, [16:0]=src.
// rs2[d] = e0 | (e1<<32); e0 always multiple of 4.
// ============================================================================

#define BKT     256     // dsts per bucket
#define CAP     12032   // queue slots per bucket (mean ~8163)
#define MAXSPAN 13056   // csr slots per bucket: CAP + 256 + 768 pad, %4==0
#define PEPB    4096    // edges per partition block

// ---------- weight prep: Wt[n][k] fp16 (n<64 -> Wl col n, n>=64 -> Wr), bias vec ----------
__global__ void k_prep_w(const float* __restrict__ Wl1, const float* __restrict__ bl1,
                         const float* __restrict__ Wr1, const float* __restrict__ br1,
                         const float* __restrict__ Wl2, const float* __restrict__ bl2,
                         const float* __restrict__ Wr2, const float* __restrict__ br2,
                         _Float16* __restrict__ Wt1, float* __restrict__ bv1,
                         _Float16* __restrict__ Wt2, float* __restrict__ bv2, int ld1) {
    int t = blockIdx.x * blockDim.x + threadIdx.x;
    int stride = gridDim.x * blockDim.x;
    int IN1 = 1 << ld1;
    for (int i = t; i < 128 * IN1; i += stride) {
        int n = i >> ld1, k = i & (IN1 - 1);
        float v = (n < 64) ? Wl1[k * 64 + n] : Wr1[k * 64 + (n - 64)];
        Wt1[n * IN1 + k] = (_Float16)v;
    }
    for (int i = t; i < 128 * 64; i += stride) {
        int n = i >> 6, k = i & 63;
        float v = (n < 64) ? Wl2[k * 64 + n] : Wr2[k * 64 + (n - 64)];
        Wt2[n * 64 + k] = (_Float16)v;
    }
    if (t < 128) {
        bv1[t] = (t < 64) ? bl1[t] : br1[t - 64];
        bv2[t] = (t < 64) ? bl2[t] : br2[t - 64];
    }
}

// ---------- node transform core: MFMA 16x16x32 f16, 64 nodes/block ----------
template<int IN, bool F32IN>
__device__ __forceinline__ void xf_block_mfma(
        const void* __restrict__ hsrc,
        const _Float16* __restrict__ Wt,   // [128][IN] fp16, n-major
        const float* __restrict__ bv,      // [128] bias = [bl | br]
        __half* __restrict__ xl, __half* __restrict__ xr,
        int N, int node0, _Float16* rows, int t) {
    constexpr int LDK = IN + 8;            // +16B pad
    constexpr int Q = IN / 4;              // 4-elem chunks per row
    for (int idx = t; idx < 64 * Q; idx += 256) {
        int nn = idx / Q;
        int kk = (idx % Q) * 4;
        int node = node0 + nn;
        half4v hv = {(_Float16)0.f, (_Float16)0.f, (_Float16)0.f, (_Float16)0.f};
        if (node < N) {
            if constexpr (F32IN) {
                float4 v = *(const float4*)((const float*)hsrc + (size_t)node * IN + kk);
                hv = half4v{(_Float16)v.x, (_Float16)v.y, (_Float16)v.z, (_Float16)v.w};
            } else {
                hv = *(const half4v*)((const _Float16*)hsrc + (size_t)node * IN + kk);
            }
        }
        *(half4v*)(rows + nn * LDK + kk) = hv;
    }
    __syncthreads();
    int lane = t & 63, w = t >> 6;
    int n0w = w * 32;
    int lr = lane & 15, lq = lane >> 4;
    f32x4 acc[4][2];
#pragma unroll
    for (int i = 0; i < 4; ++i)
#pragma unroll
        for (int j = 0; j < 2; ++j) acc[i][j] = {0.f, 0.f, 0.f, 0.f};
    const _Float16* arow = rows + lr * LDK + lq * 8;
    const _Float16* brow = Wt + (size_t)(n0w + lr) * IN + lq * 8;
#pragma unroll
    for (int k0 = 0; k0 < IN; k0 += 32) {
        half8 a0 = *(const half8*)(arow + k0);
        half8 a1 = *(const half8*)(arow + 16 * LDK + k0);
        half8 a2 = *(const half8*)(arow + 32 * LDK + k0);
        half8 a3 = *(const half8*)(arow + 48 * LDK + k0);
        half8 b0 = *(const half8*)(brow + k0);
        half8 b1 = *(const half8*)(brow + 16 * IN + k0);
        acc[0][0] = __builtin_amdgcn_mfma_f32_16x16x32_f16(a0, b0, acc[0][0], 0, 0, 0);
        acc[1][0] = __builtin_amdgcn_mfma_f32_16x16x32_f16(a1, b0, acc[1][0], 0, 0, 0);
        acc[2][0] = __builtin_amdgcn_mfma_f32_16x16x32_f16(a2, b0, acc[2][0], 0, 0, 0);
        acc[3][0] = __builtin_amdgcn_mfma_f32_16x16x32_f16(a3, b0, acc[3][0], 0, 0, 0);
        acc[0][1] = __builtin_amdgcn_mfma_f32_16x16x32_f16(a0, b1, acc[0][1], 0, 0, 0);
        acc[1][1] = __builtin_amdgcn_mfma_f32_16x16x32_f16(a1, b1, acc[1][1], 0, 0, 0);
        acc[2][1] = __builtin_amdgcn_mfma_f32_16x16x32_f16(a2, b1, acc[2][1], 0, 0, 0);
        acc[3][1] = __builtin_amdgcn_mfma_f32_16x16x32_f16(a3, b1, acc[3][1], 0, 0, 0);
    }
    float bia0 = bv[n0w + lr];
    float bia1 = bv[n0w + 16 + lr];
#pragma unroll
    for (int ni = 0; ni < 2; ++ni) {
        int dim = n0w + ni * 16 + lr;
        __half* dst = (dim < 64) ? xl : xr;
        int dd = dim & 63;
        float bb = ni ? bia1 : bia0;
#pragma unroll
        for (int mi = 0; mi < 4; ++mi) {
#pragma unroll
            for (int r = 0; r < 4; ++r) {
                int node = node0 + mi * 16 + lq * 4 + r;
                if (node < N)
                    dst[((size_t)node << 6) + dd] = __float2half(acc[mi][ni][r] + bb);
            }
        }
    }
}

// shared-memory union: xf rows (17.4 KB max) vs partition arrays (3 KB)
union XfPartSmem {
    _Float16 rows[64 * 136];
    struct { int lh[256]; int lbase[256]; int lcur[256]; } p;
};

// FUSED: blocks [0,nbXF) = layer-1 node transform; blocks [nbXF,..) = partition
template<int IN>
__global__ void k_xf1_part(
        const float* __restrict__ h,
        const _Float16* __restrict__ Wt, const float* __restrict__ bv,
        __half* __restrict__ xl, __half* __restrict__ xr, int N, int nbXF,
        const int* __restrict__ ei, const float* __restrict__ ea,
        int* __restrict__ qtail, u64* __restrict__ queue, int E) {
    __shared__ XfPartSmem sm;
    int t = threadIdx.x;
    if (blockIdx.x < nbXF) {
        xf_block_mfma<IN, true>(h, Wt, bv, xl, xr, N, blockIdx.x * 64, sm.rows, t);
    } else {
        int pb = blockIdx.x - nbXF;
        sm.p.lh[t] = 0; sm.p.lcur[t] = 0;
        __syncthreads();
        int base = pb * PEPB;
        int end = base + PEPB; if (end > E) end = E;
        for (int e = base + t; e < end; e += 256) {
            int d = ei[E + e];
            atomicAdd(&sm.p.lh[d >> 8], 1);
        }
        __syncthreads();
        if (sm.p.lh[t]) sm.p.lbase[t] = atomicAdd(&qtail[t], sm.p.lh[t]);
        __syncthreads();
        for (int e = base + t; e < end; e += 256) {
            int d = ei[E + e];
            int src = ei[e];
            float a = ea[e];
            int b = d >> 8;
            int idx = atomicAdd(&sm.p.lcur[b], 1);
            unsigned aq = (unsigned)(a * 16777216.0f);    // fixed-24, attr in [0,1)
            queue[(size_t)b * CAP + sm.p.lbase[b] + idx] =
                (((u64)aq) << 25) | (((u64)(d & 255)) << 17) | (unsigned)src;
        }
    }
}

__device__ __forceinline__ unsigned attr_q15(float a) {
    unsigned short hb = __builtin_bit_cast(unsigned short, (_Float16)a);
    return (unsigned)(hb >> 1);       // attr in [0,1) -> fp16 top bit 0
}

// one block per 256-dst bucket (196 blocks x 1024 thr), single queue read,
// v18: 4-way replicated stat/fill counters (quadrant t>>8 owns a copy) ->
// 4x less same-address LDS-atomic serialization in count AND scatter passes.
// stat4 unions with lcsr (stat4 dead before first lcsr write).
__global__ void __launch_bounds__(1024)
k_build(const u64* __restrict__ queue, const int* __restrict__ qtail,
        u64* __restrict__ rs2, unsigned* __restrict__ csr, int N) {
    __shared__ union {
        u64 stat4[4][BKT];            // 8 KB (count phase)
        unsigned lcsr[MAXSPAN];       // 52.2 KB (scatter phase)
    } bu;
    __shared__ int fill4[4][BKT];     // 4 KB
    __shared__ int sc[BKT];           // 1 KB
    int t = threadIdx.x, b = blockIdx.x;
    int quad = t >> 8;
    if (t < 1024) (&bu.stat4[0][0])[t] = 0;   // zero all 4 copies (flat)
    __syncthreads();
    int cnt = qtail[b];
    size_t q0 = (size_t)b * CAP;
    u64 rec[12];                      // CAP/1024 = 11.75 -> max 12 per thread
#pragma unroll
    for (int k = 0; k < 12; ++k) {
        int i = t + k * 1024;
        rec[k] = (i < cnt) ? queue[q0 + i] : 0;
    }
#pragma unroll
    for (int k = 0; k < 12; ++k) {
        int i = t + k * 1024;
        if (i < cnt) {
            u64 r = rec[k];
            atomicAdd(&bu.stat4[quad][(int)((r >> 17) & (BKT - 1))],
                      (1ULL << 32) | (unsigned)(r >> 25));
        }
    }
    __syncthreads();
    int dg = b * BKT + t;
    u64 p = 0;
    int c0cnt = 0, c1cnt = 0, c2cnt = 0;
    if (t < BKT) {
        u64 s0 = bu.stat4[0][t], s1 = bu.stat4[1][t];
        u64 s2 = bu.stat4[2][t], s3 = bu.stat4[3][t];
        p = s0 + s1 + s2 + s3;
        c0cnt = (int)(s0 >> 32); c1cnt = (int)(s1 >> 32); c2cnt = (int)(s2 >> 32);
    }
    int deg = (int)(p >> 32);
    int v = (t < BKT && dg < N) ? ((deg + 1 + 3) & ~3) : 0;   // pad span to x4
    if (t < BKT) sc[t] = v;
    __syncthreads();
    for (int off = 1; off < BKT; off <<= 1) {
        int a = (t >= off && t < BKT) ? sc[t - off] : 0;
        __syncthreads();
        if (t < BKT) sc[t] += a;
        __syncthreads();
    }
    int c0 = b * MAXSPAN;
    int selfpos = -1;
    unsigned selfrec = 0;
    if (t < BKT && dg < N) {
        int basel = sc[t] - v;   // exclusive, multiple of 4
        rs2[dg] = (u64)(unsigned)(c0 + basel) | (((u64)(unsigned)(c0 + basel + deg + 1)) << 32);
        // per-copy scatter bases: quadrant c fills [basel+Σ_{c'<c}cnt, +cnt_c)
        fill4[0][t] = basel;
        fill4[1][t] = basel + c0cnt;
        fill4[2][t] = basel + c0cnt + c1cnt;
        fill4[3][t] = basel + c0cnt + c1cnt + c2cnt;
        float mean = ((float)(unsigned)p * (1.0f / 16777216.0f)) / fmaxf((float)deg, 1.0f);
        selfpos = basel + deg;
        selfrec = (attr_q15(mean) << 17) | (unsigned)dg;
    }
    __syncthreads();   // stat4 reads done; fill4 ready -> lcsr may be written
    if (selfpos >= 0 && selfpos < MAXSPAN) bu.lcsr[selfpos] = selfrec;
#pragma unroll
    for (int k = 0; k < 12; ++k) {
        int i = t + k * 1024;
        if (i < cnt) {
            u64 r = rec[k];
            int dl = (int)((r >> 17) & (BKT - 1));
            int pos = atomicAdd(&fill4[quad][dl], 1);
            float av = (float)(unsigned)(r >> 25) * (1.0f / 16777216.0f);
            if (pos < MAXSPAN) bu.lcsr[pos] = (attr_q15(av) << 17) | (unsigned)(r & 0x1FFFFu);
        }
    }
    __syncthreads();
    int span = sc[BKT - 1];           // total slots used (incl. pads, garbage ok)
    if (span > MAXSPAN) span = MAXSPAN;
    for (int j = t; j < span; j += 1024) csr[c0 + j] = bu.lcsr[j];
}

// ---------- node transform (standalone, layer 2: IN=64, fp16 input) ----------
__global__ void k_node_xf(const __half* __restrict__ h,
                          const _Float16* __restrict__ Wt, const float* __restrict__ bv,
                          __half* __restrict__ xl, __half* __restrict__ xr, int N) {
    __shared__ _Float16 rows[64 * 72];
    xf_block_mfma<64, false>(h, Wt, bv, xl, xr, N, blockIdx.x * 64, rows, threadIdx.x);
}

// ---------- DPP butterfly add: cross-lane sum within 16-lane rows ----------
template<int CTRL>
__device__ __forceinline__ float dpp_add(float c) {
    int t = __builtin_amdgcn_update_dpp(0, __builtin_bit_cast(int, c),
                                        CTRL, 0xF, 0xF, true);
    return c + __builtin_bit_cast(float, t);
}

// ---------- edge micro-step: one 4-edge group (att pre-scaled by log2e) ----------
#define EDGE_GROUP(r, xh, cc)                                                  \
    {                                                                          \
        _Float16 ah = __builtin_bit_cast(_Float16, (unsigned short)((r >> 16) & 0xFFFEu)); \
        half2v aa = {ah, ah};                                                  \
        half2v x01 = {xh.x, xh.y}, x23 = {xh.z, xh.w};                         \
        half2v v01 = aa * We01 + (x01 + xr01);                                 \
        half2v v23 = aa * We23 + (x23 + xr23);                                 \
        half2v s01 = __builtin_elementwise_max(v01, v01 * k02);                \
        half2v s23 = __builtin_elementwise_max(v23, v23 * k02);                \
        cc = __builtin_amdgcn_fdot2(s01, at01, 0.f, false);                    \
        cc = __builtin_amdgcn_fdot2(s23, at23, cc, false);                     \
    }

// ---------- fused edge phase: wave/dst, 16x4 packed fp16, depth-1 pipeline ----
__global__ void k_attn(const __half* __restrict__ xl, const __half* __restrict__ xr,
                       const unsigned* __restrict__ csr, const u64* __restrict__ rs2,
                       const float* __restrict__ We, const float* __restrict__ att,
                       const float* __restrict__ bias,
                       __half* __restrict__ hout, int N) {
    int lane = threadIdx.x & 63;
    int d = (int)(((size_t)blockIdx.x * blockDim.x + threadIdx.x) >> 6);
    if (d >= N) return;
    int eq = lane >> 4;           // which of 4 concurrent edges
    int fl = lane & 15;           // which 4-dim chunk of the 64 dims
    const float LOG2E = 1.44269504088896340736f;
    float4 Wef  = *(const float4*)(We + fl * 4);
    float4 attf = *(const float4*)(att + fl * 4);
    half2v We01 = {(_Float16)Wef.x, (_Float16)Wef.y};
    half2v We23 = {(_Float16)Wef.z, (_Float16)Wef.w};
    half2v at01 = {(_Float16)(attf.x * LOG2E), (_Float16)(attf.y * LOG2E)};
    half2v at23 = {(_Float16)(attf.z * LOG2E), (_Float16)(attf.w * LOG2E)};
    unsigned flo = (unsigned)fl * 4u;
    half4v xrh = *(const half4v*)(xr + (((unsigned)d << 6) | flo));
    half2v xr01 = {xrh.x, xrh.y}, xr23 = {xrh.z, xrh.w};
    const half2v k02 = {(_Float16)0.2f, (_Float16)0.2f};
    u64 rr = rs2[d];
    int e0 = __builtin_amdgcn_readfirstlane((int)(unsigned)rr);
    int e1 = __builtin_amdgcn_readfirstlane((int)(unsigned)(rr >> 32));
    float l = 0.f;
    f32x2 Oa = {0.f, 0.f}, Ob = {0.f, 0.f};
    int e = e0;
    uint4 rv = *(const uint4*)(csr + e + (eq << 2));       // csr padded +256
    half4v xA = *(const half4v*)(xl + (((rv.x & 0x1FFFFu) << 6) | flo));
    half4v xB = *(const half4v*)(xl + (((rv.y & 0x1FFFFu) << 6) | flo));
    half4v xC = *(const half4v*)(xl + (((rv.z & 0x1FFFFu) << 6) | flo));
    half4v xD = *(const half4v*)(xl + (((rv.w & 0x1FFFFu) << 6) | flo));
    for (; e + 16 <= e1; e += 16) {     // 16 edges in flight; e%4==0 (padded spans)
        uint4 rvn = *(const uint4*)(csr + e + 16 + (eq << 2));
        float cA, cB, cC, cD;
        EDGE_GROUP(rv.x, xA, cA);
        EDGE_GROUP(rv.y, xB, cB);
        EDGE_GROUP(rv.z, xC, cC);
        EDGE_GROUP(rv.w, xD, cD);
        half4v nA = *(const half4v*)(xl + (((rvn.x & 0x1FFFFu) << 6) | flo));
        half4v nB = *(const half4v*)(xl + (((rvn.y & 0x1FFFFu) << 6) | flo));
        half4v nC = *(const half4v*)(xl + (((rvn.z & 0x1FFFFu) << 6) | flo));
        half4v nD = *(const half4v*)(xl + (((rvn.w & 0x1FFFFu) << 6) | flo));
        cA = dpp_add<0xB1>(cA);  cB = dpp_add<0xB1>(cB);
        cC = dpp_add<0xB1>(cC);  cD = dpp_add<0xB1>(cD);
        cA = dpp_add<0x4E>(cA);  cB = dpp_add<0x4E>(cB);
        cC = dpp_add<0x4E>(cC);  cD = dpp_add<0x4E>(cD);
        cA = dpp_add<0x141>(cA); cB = dpp_add<0x141>(cB);
        cC = dpp_add<0x141>(cC); cD = dpp_add<0x141>(cD);
        cA = dpp_add<0x140>(cA); cB = dpp_add<0x140>(cB);
        cC = dpp_add<0x140>(cC); cD = dpp_add<0x140>(cD);
        float qA = __builtin_exp2f(cA), qB = __builtin_exp2f(cB);
        float qC = __builtin_exp2f(cC), qD = __builtin_exp2f(cD);
        l += (qA + qB) + (qC + qD);
        f32x2 qA2 = {qA, qA}, qB2 = {qB, qB}, qC2 = {qC, qC}, qD2 = {qD, qD};
        f32x2 xa01 = {(float)xA.x, (float)xA.y}, xa23 = {(float)xA.z, (float)xA.w};
        f32x2 xb01 = {(float)xB.x, (float)xB.y}, xb23 = {(float)xB.z, (float)xB.w};
        f32x2 xc01 = {(float)xC.x, (float)xC.y}, xc23 = {(float)xC.z, (float)xC.w};
        f32x2 xd01 = {(float)xD.x, (float)xD.y}, xd23 = {(float)xD.z, (float)xD.w};
        Oa = __builtin_elementwise_fma(qA2, xa01, Oa);
        Oa = __builtin_elementwise_fma(qB2, xb01, Oa);
        Oa = __builtin_elementwise_fma(qC2, xc01, Oa);
        Oa = __builtin_elementwise_fma(qD2, xd01, Oa);
        Ob = __builtin_elementwise_fma(qA2, xa23, Ob);
        Ob = __builtin_elementwise_fma(qB2, xb23, Ob);
        Ob = __builtin_elementwise_fma(qC2, xc23, Ob);
        Ob = __builtin_elementwise_fma(qD2, xd23, Ob);
        rv = rvn; xA = nA; xB = nB; xC = nC; xD = nD;
    }
    for (; e < e1; e += 4) {            // tail with clamp
        int ee = e + eq;
        bool valid = ee < e1;
        unsigned r = csr[valid ? ee : (e1 - 1)];
        half4v xh = *(const half4v*)(xl + (((r & 0x1FFFFu) << 6) | flo));
        float c;
        EDGE_GROUP(r, xh, c);
        c = dpp_add<0xB1>(c);
        c = dpp_add<0x4E>(c);
        c = dpp_add<0x141>(c);
        c = dpp_add<0x140>(c);
        float q = valid ? __builtin_exp2f(c) : 0.f;
        l += q;
        Oa.x = fmaf(q, (float)xh.x, Oa.x);
        Oa.y = fmaf(q, (float)xh.y, Oa.y);
        Ob.x = fmaf(q, (float)xh.z, Ob.x);
        Ob.y = fmaf(q, (float)xh.w, Ob.y);
    }
#pragma unroll
    for (int mm = 16; mm <= 32; mm <<= 1) {
        l    += __shfl_xor(l, mm, 64);
        Oa.x += __shfl_xor(Oa.x, mm, 64);
        Oa.y += __shfl_xor(Oa.y, mm, 64);
        Ob.x += __shfl_xor(Ob.x, mm, 64);
        Ob.y += __shfl_xor(Ob.y, mm, 64);
    }
    if (eq == 0) {
        float inv = 1.0f / (l + 1e-16f);
        float4 b4 = *(const float4*)(bias + fl * 4);
        float4 res;
        res.x = fmaf(Oa.x, inv, b4.x);
        res.y = fmaf(Oa.y, inv, b4.y);
        res.z = fmaf(Ob.x, inv, b4.z);
        res.w = fmaf(Ob.y, inv, b4.w);
        res.x = res.x > 0.f ? res.x : __expf(res.x) - 1.f;
        res.y = res.y > 0.f ? res.y : __expf(res.y) - 1.f;
        res.z = res.z > 0.f ? res.z : __expf(res.z) - 1.f;
        res.w = res.w > 0.f ? res.w : __expf(res.w) - 1.f;
        half4v rh = {(_Float16)res.x, (_Float16)res.y, (_Float16)res.z, (_Float16)res.w};
        *(half4v*)(hout + (((size_t)d << 6) | flo)) = rh;
    }
}

// ---------- pool (+ fused head), fp16 h, 16 nodes/wave + block-LDS slots ----
// Release via s_waitcnt vmcnt(0) (atomics are device-scope); acquire
// __threadfence() only in the single last-done block (v17 fence fix).
__global__ void k_pool_head(const __half* __restrict__ h, const int* __restrict__ batch,
                            float* __restrict__ pooled, float* __restrict__ gcnt,
                            int N, int* __restrict__ done,
                            const float* __restrict__ W1, const float* __restrict__ b1,
                            const float* __restrict__ gam, const float* __restrict__ bet,
                            const float* __restrict__ mu, const float* __restrict__ var,
                            const float* __restrict__ W3, const float* __restrict__ b3,
                            float* __restrict__ out, int G) {
    __shared__ float sacc[4][65];     // 4 group slots x (64 dims + count)
    int tid = threadIdx.x;
    int lane = tid & 63, w = tid >> 6;
    int blockBegin = blockIdx.x * 64;
    for (int i = tid; i < 4 * 65; i += 256) (&sacc[0][0])[i] = 0.f;
    __syncthreads();
    if (blockBegin < N) {
        int gfirst = batch[blockBegin];
        int begin = blockBegin + w * 16;
        if (begin < N) {
            int bidx = begin + (lane & 15);
            int bval = batch[bidx < N ? bidx : (N - 1)];
            float hv[16];                 // 16 regs: loads genuinely in flight
#pragma unroll
            for (int j = 0; j < 16; ++j) {
                int n = begin + j;
                hv[j] = (n < N) ? __half2float(h[((size_t)n << 6) + lane]) : 0.f;
            }
            int g = __shfl(bval, 0, 64);
            float acc = 0.f, cnt = 0.f;
#pragma unroll
            for (int j = 0; j < 16; ++j) {
                if (begin + j < N) {          // wave-uniform
                    int gn = __shfl(bval, j, 64);
                    if (gn != g) {
                        int slot = g - gfirst;
                        if (slot < 4) {
                            atomicAdd(&sacc[slot][lane], acc);
                            if (lane == 0) atomicAdd(&sacc[slot][64], cnt);
                        } else {
                            atomicAdd(&pooled[((size_t)g << 6) + lane], acc);
                            if (lane == 0) atomicAdd(&gcnt[g], cnt);
                        }
                        g = gn; acc = 0.f; cnt = 0.f;
                    }
                    acc += hv[j];
                    cnt += 1.f;
                }
            }
            int slot = g - gfirst;
            if (slot < 4) {
                atomicAdd(&sacc[slot][lane], acc);
                if (lane == 0) atomicAdd(&sacc[slot][64], cnt);
            } else {
                atomicAdd(&pooled[((size_t)g << 6) + lane], acc);
                if (lane == 0) atomicAdd(&gcnt[g], cnt);
            }
        }
        __syncthreads();
        // flush: wave w owns slot w
        float c = sacc[w][64];
        if (c != 0.f) {
            int g = gfirst + w;
            atomicAdd(&pooled[((size_t)g << 6) + lane], sacc[w][lane]);
            if (lane == 0) atomicAdd(&gcnt[g], c);
        }
    }
    // release: drain our device-scope atomics. NOT __threadfence() (= full-L2
    // writeback per wave on non-coherent per-XCD L2s -> was the pool floor).
    asm volatile("s_waitcnt vmcnt(0)" ::: "memory");
    __syncthreads();
    __shared__ int lastFlag;
    if (tid == 0) lastFlag = (atomicAdd(done, 1) == (int)gridDim.x - 1);
    __syncthreads();
    if (lastFlag && tid < G) {
        __threadfence();   // acquire: invalidate stale local cache lines (1 block)
        int g = tid;
        float inv = 1.0f / fmaxf(gcnt[g], 1.0f);
        float pr[64];
        for (int k = 0; k < 64; ++k) pr[k] = pooled[((size_t)g << 6) + k] * inv;
        float o = b3[0];
        for (int j = 0; j < 32; ++j) {
            float z = b1[j];
            for (int k = 0; k < 64; ++k) z += pr[k] * W1[k * 32 + j];
            z = fmaxf(z, 0.f);
            z = (z - mu[j]) / sqrtf(var[j] + 1e-5f) * gam[j] + bet[j];
            o += z * W3[j];
        }
        out[g] = o;
    }
}

// ---------- launch ----------
extern "C" void kernel_launch(void* const* d_in, const int* in_sizes, int n_in,
                              void* d_out, int out_size, void* d_ws, size_t ws_size,
                              hipStream_t stream) {
    const float* x    = (const float*)d_in[0];
    const int*   ei   = (const int*)d_in[1];
    const float* ea   = (const float*)d_in[2];
    const int*   batch= (const int*)d_in[3];
    const float* Wl1  = (const float*)d_in[4];
    const float* bl1  = (const float*)d_in[5];
    const float* Wr1  = (const float*)d_in[6];
    const float* br1  = (const float*)d_in[7];
    const float* We1  = (const float*)d_in[8];
    const float* att1 = (const float*)d_in[9];
    const float* bi1  = (const float*)d_in[10];
    const float* Wl2  = (const float*)d_in[11];
    const float* bl2  = (const float*)d_in[12];
    const float* Wr2  = (const float*)d_in[13];
    const float* br2  = (const float*)d_in[14];
    const float* We2  = (const float*)d_in[15];
    const float* att2 = (const float*)d_in[16];
    const float* bi2  = (const float*)d_in[17];
    const float* Wf1  = (const float*)d_in[18];
    const float* bf1  = (const float*)d_in[19];
    const float* gam  = (const float*)d_in[20];
    const float* bet  = (const float*)d_in[21];
    const float* mu   = (const float*)d_in[22];
    const float* var  = (const float*)d_in[23];
    const float* Wf3  = (const float*)d_in[24];
    const float* bf3  = (const float*)d_in[25];

    const int N    = in_sizes[3];          // 50000
    const int E    = in_sizes[2];          // 1600000
    const int INd  = in_sizes[0] / N;      // 128
    const int ld1  = (INd == 128) ? 7 : 6;
    const int G    = out_size;             // 64
    const int NB   = (N + BKT - 1) / BKT;  // 256-dst buckets (196)

    // workspace carve-up (256B aligned)
    char* w = (char*)d_ws;
    auto carve = [&](size_t bytes) { char* p = w; w += (bytes + 255) & ~(size_t)255; return p; };
    __half*   xl       = (__half*)  carve((size_t)N * 64 * 2);
    __half*   xr       = (__half*)  carve((size_t)N * 64 * 2);
    __half*   hbuf     = (__half*)  carve((size_t)N * 64 * 2);   // fp16
    unsigned* csr      = (unsigned*)carve(((size_t)NB * MAXSPAN + 256) * 4);  // +prefetch pad
    u64*      queue    = (u64*)     carve((size_t)NB * CAP * 8);
    u64*      rs2      = (u64*)     carve((size_t)N * 8);
    // zeroed region: qtail + pooled + gcnt + done (contiguous, single memset)
    char*     z0       = w;
    int*      qtail    = (int*)     carve((size_t)(NB + 1) * 4);
    float*    pooled   = (float*)   carve((size_t)G * 64 * 4);
    float*    gcnt     = (float*)   carve((size_t)G * 4);
    int*      done     = (int*)     carve(256);
    size_t    zbytes   = (size_t)(w - z0);
    _Float16* Wt1      = (_Float16*)carve((size_t)128 * 128 * 2);
    float*    bv1      = (float*)   carve(128 * 4);
    _Float16* Wt2      = (_Float16*)carve((size_t)128 * 64 * 2);
    float*    bv2      = (float*)   carve(128 * 4);

    const int TB = 256;
    const int nbXF = (N + 63) / 64;              // node-transform blocks
    const int attnBlocks = (N + 3) / 4;          // wave per dst, 4 waves/block
    const int nbPart = (E + PEPB - 1) / PEPB;    // 391 partition blocks
    const int nbPool = (N + 63) / 64;            // 64 nodes per pool block

    // ---- zero counters (single memset) ----
    hipMemsetAsync(z0, 0, zbytes, stream);

    // ---- weight prep (fp16, transposed, fused bias) ----
    k_prep_w<<<32, TB, 0, stream>>>(Wl1, bl1, Wr1, br1, Wl2, bl2, Wr2, br2,
                                    Wt1, bv1, Wt2, bv2, ld1);

    // ---- fused: layer-1 node transform (MFMA) || edge partition ----
    if (INd == 128)
        k_xf1_part<128><<<nbXF + nbPart, TB, 0, stream>>>(x, Wt1, bv1, xl, xr, N, nbXF,
                                                          ei, ea, qtail, queue, E);
    else
        k_xf1_part<64><<<nbXF + nbPart, TB, 0, stream>>>(x, Wt1, bv1, xl, xr, N, nbXF,
                                                         ei, ea, qtail, queue, E);
    k_build<<<NB, 1024, 0, stream>>>(queue, qtail, rs2, csr, N);

    // ---- layer 1 edge phase ----
    k_attn<<<attnBlocks, TB, 0, stream>>>(xl, xr, csr, rs2, We1, att1, bi1, hbuf, N);

    // ---- layer 2 ----
    k_node_xf<<<nbXF, TB, 0, stream>>>(hbuf, Wt2, bv2, xl, xr, N);
    k_attn<<<attnBlocks, TB, 0, stream>>>(xl, xr, csr, rs2, We2, att2, bi2, hbuf, N);

    // ---- pool + head (fused) ----
    k_pool_head<<<nbPool, TB, 0, stream>>>(
        hbuf, batch, pooled, gcnt, N, done,
        Wf1, bf1, gam, bet, mu, var, Wf3, bf3, (float*)d_out, G);
}

// Round 13
// 287.449 us; speedup vs baseline: 1.0267x; 1.0267x over previous
//
#include <hip/hip_runtime.h>
#include <hip/hip_fp16.h>
#include <math.h>

typedef unsigned long long u64;
typedef __attribute__((ext_vector_type(2))) _Float16 half2v;
typedef __attribute__((ext_vector_type(4))) _Float16 half4v;
typedef __attribute__((ext_vector_type(8))) _Float16 half8;
typedef __attribute__((ext_vector_type(4))) float f32x4;
typedef __attribute__((ext_vector_type(2))) float f32x2;

// ============================================================================
// v19 = v17 (292.4us, best measured) — final configuration.
// v18 POST-MORTEM: k_build 4-way replicated LDS counters NEUTRAL (295.1,
//   within noise) -> k_build's LDS-atomic serialization was not the hidden
//   whale; reverted to the simpler v17 k_build.
// v17: pool fence fix (per-wave __threadfence = full-L2 writeback on gfx950's
//   non-coherent per-XCD L2s was a 50-80us pool floor across FIVE pool
//   variants; release = s_waitcnt vmcnt(0) since all hot-path writes are
//   device-scope atomics; acquire fence only in the single last-done block).
// v16: pool 16 nodes/wave + block-LDS group slots. v15: k_build single-pass
//   reg-cached queue, hbuf fp16, single memset. v14: attn depth-1 pipeline.
// v13 PM: direct global-atomic scatter = 15x write amp (99MB) -> REVERTED;
//   the queue+LDS-build earns its time by converting random 4B scatter into
//   full-line writes.
// v12: 256-dst buckets (64-dst = 1.6x queue write amp, REVERTED) + attn diet
//   (uint4 csr, 32-bit offsets, exp2-direct, pk_fma, fast ELU).
// v10: DPP butterfly (0xB1/0x4E/0x141/0x140). v9: pool reg-prefetch.
// v7: MFMA 16x16x32 node transforms (was scalar VALU: 160->49us).
// Queue record u64: [48:25]=attr fixed-24, [24:17]=dst&255, [16:0]=src.
// csr record u32: [31:17]=fp16-attr-bits>>1, [16:0]=src.
// rs2[d] = e0 | (e1<<32); e0 always multiple of 4.
// ============================================================================

#define BKT     256     // dsts per bucket
#define CAP     12032   // queue slots per bucket (mean ~8163)
#define MAXSPAN 13056   // csr slots per bucket: CAP + 256 + 768 pad, %4==0
#define PEPB    4096    // edges per partition block

// ---------- weight prep: Wt[n][k] fp16 (n<64 -> Wl col n, n>=64 -> Wr), bias vec ----------
__global__ void k_prep_w(const float* __restrict__ Wl1, const float* __restrict__ bl1,
                         const float* __restrict__ Wr1, const float* __restrict__ br1,
                         const float* __restrict__ Wl2, const float* __restrict__ bl2,
                         const float* __restrict__ Wr2, const float* __restrict__ br2,
                         _Float16* __restrict__ Wt1, float* __restrict__ bv1,
                         _Float16* __restrict__ Wt2, float* __restrict__ bv2, int ld1) {
    int t = blockIdx.x * blockDim.x + threadIdx.x;
    int stride = gridDim.x * blockDim.x;
    int IN1 = 1 << ld1;
    for (int i = t; i < 128 * IN1; i += stride) {
        int n = i >> ld1, k = i & (IN1 - 1);
        float v = (n < 64) ? Wl1[k * 64 + n] : Wr1[k * 64 + (n - 64)];
        Wt1[n * IN1 + k] = (_Float16)v;
    }
    for (int i = t; i < 128 * 64; i += stride) {
        int n = i >> 6, k = i & 63;
        float v = (n < 64) ? Wl2[k * 64 + n] : Wr2[k * 64 + (n - 64)];
        Wt2[n * 64 + k] = (_Float16)v;
    }
    if (t < 128) {
        bv1[t] = (t < 64) ? bl1[t] : br1[t - 64];
        bv2[t] = (t < 64) ? bl2[t] : br2[t - 64];
    }
}

// ---------- node transform core: MFMA 16x16x32 f16, 64 nodes/block ----------
template<int IN, bool F32IN>
__device__ __forceinline__ void xf_block_mfma(
        const void* __restrict__ hsrc,
        const _Float16* __restrict__ Wt,   // [128][IN] fp16, n-major
        const float* __restrict__ bv,      // [128] bias = [bl | br]
        __half* __restrict__ xl, __half* __restrict__ xr,
        int N, int node0, _Float16* rows, int t) {
    constexpr int LDK = IN + 8;            // +16B pad
    constexpr int Q = IN / 4;              // 4-elem chunks per row
    for (int idx = t; idx < 64 * Q; idx += 256) {
        int nn = idx / Q;
        int kk = (idx % Q) * 4;
        int node = node0 + nn;
        half4v hv = {(_Float16)0.f, (_Float16)0.f, (_Float16)0.f, (_Float16)0.f};
        if (node < N) {
            if constexpr (F32IN) {
                float4 v = *(const float4*)((const float*)hsrc + (size_t)node * IN + kk);
                hv = half4v{(_Float16)v.x, (_Float16)v.y, (_Float16)v.z, (_Float16)v.w};
            } else {
                hv = *(const half4v*)((const _Float16*)hsrc + (size_t)node * IN + kk);
            }
        }
        *(half4v*)(rows + nn * LDK + kk) = hv;
    }
    __syncthreads();
    int lane = t & 63, w = t >> 6;
    int n0w = w * 32;
    int lr = lane & 15, lq = lane >> 4;
    f32x4 acc[4][2];
#pragma unroll
    for (int i = 0; i < 4; ++i)
#pragma unroll
        for (int j = 0; j < 2; ++j) acc[i][j] = {0.f, 0.f, 0.f, 0.f};
    const _Float16* arow = rows + lr * LDK + lq * 8;
    const _Float16* brow = Wt + (size_t)(n0w + lr) * IN + lq * 8;
#pragma unroll
    for (int k0 = 0; k0 < IN; k0 += 32) {
        half8 a0 = *(const half8*)(arow + k0);
        half8 a1 = *(const half8*)(arow + 16 * LDK + k0);
        half8 a2 = *(const half8*)(arow + 32 * LDK + k0);
        half8 a3 = *(const half8*)(arow + 48 * LDK + k0);
        half8 b0 = *(const half8*)(brow + k0);
        half8 b1 = *(const half8*)(brow + 16 * IN + k0);
        acc[0][0] = __builtin_amdgcn_mfma_f32_16x16x32_f16(a0, b0, acc[0][0], 0, 0, 0);
        acc[1][0] = __builtin_amdgcn_mfma_f32_16x16x32_f16(a1, b0, acc[1][0], 0, 0, 0);
        acc[2][0] = __builtin_amdgcn_mfma_f32_16x16x32_f16(a2, b0, acc[2][0], 0, 0, 0);
        acc[3][0] = __builtin_amdgcn_mfma_f32_16x16x32_f16(a3, b0, acc[3][0], 0, 0, 0);
        acc[0][1] = __builtin_amdgcn_mfma_f32_16x16x32_f16(a0, b1, acc[0][1], 0, 0, 0);
        acc[1][1] = __builtin_amdgcn_mfma_f32_16x16x32_f16(a1, b1, acc[1][1], 0, 0, 0);
        acc[2][1] = __builtin_amdgcn_mfma_f32_16x16x32_f16(a2, b1, acc[2][1], 0, 0, 0);
        acc[3][1] = __builtin_amdgcn_mfma_f32_16x16x32_f16(a3, b1, acc[3][1], 0, 0, 0);
    }
    float bia0 = bv[n0w + lr];
    float bia1 = bv[n0w + 16 + lr];
#pragma unroll
    for (int ni = 0; ni < 2; ++ni) {
        int dim = n0w + ni * 16 + lr;
        __half* dst = (dim < 64) ? xl : xr;
        int dd = dim & 63;
        float bb = ni ? bia1 : bia0;
#pragma unroll
        for (int mi = 0; mi < 4; ++mi) {
#pragma unroll
            for (int r = 0; r < 4; ++r) {
                int node = node0 + mi * 16 + lq * 4 + r;
                if (node < N)
                    dst[((size_t)node << 6) + dd] = __float2half(acc[mi][ni][r] + bb);
            }
        }
    }
}

// shared-memory union: xf rows (17.4 KB max) vs partition arrays (3 KB)
union XfPartSmem {
    _Float16 rows[64 * 136];
    struct { int lh[256]; int lbase[256]; int lcur[256]; } p;
};

// FUSED: blocks [0,nbXF) = layer-1 node transform; blocks [nbXF,..) = partition
template<int IN>
__global__ void k_xf1_part(
        const float* __restrict__ h,
        const _Float16* __restrict__ Wt, const float* __restrict__ bv,
        __half* __restrict__ xl, __half* __restrict__ xr, int N, int nbXF,
        const int* __restrict__ ei, const float* __restrict__ ea,
        int* __restrict__ qtail, u64* __restrict__ queue, int E) {
    __shared__ XfPartSmem sm;
    int t = threadIdx.x;
    if (blockIdx.x < nbXF) {
        xf_block_mfma<IN, true>(h, Wt, bv, xl, xr, N, blockIdx.x * 64, sm.rows, t);
    } else {
        int pb = blockIdx.x - nbXF;
        sm.p.lh[t] = 0; sm.p.lcur[t] = 0;
        __syncthreads();
        int base = pb * PEPB;
        int end = base + PEPB; if (end > E) end = E;
        for (int e = base + t; e < end; e += 256) {
            int d = ei[E + e];
            atomicAdd(&sm.p.lh[d >> 8], 1);
        }
        __syncthreads();
        if (sm.p.lh[t]) sm.p.lbase[t] = atomicAdd(&qtail[t], sm.p.lh[t]);
        __syncthreads();
        for (int e = base + t; e < end; e += 256) {
            int d = ei[E + e];
            int src = ei[e];
            float a = ea[e];
            int b = d >> 8;
            int idx = atomicAdd(&sm.p.lcur[b], 1);
            unsigned aq = (unsigned)(a * 16777216.0f);    // fixed-24, attr in [0,1)
            queue[(size_t)b * CAP + sm.p.lbase[b] + idx] =
                (((u64)aq) << 25) | (((u64)(d & 255)) << 17) | (unsigned)src;
        }
    }
}

__device__ __forceinline__ unsigned attr_q15(float a) {
    unsigned short hb = __builtin_bit_cast(unsigned short, (_Float16)a);
    return (unsigned)(hb >> 1);       // attr in [0,1) -> fp16 top bit 0
}

// one block per 256-dst bucket (196 blocks x 1024 thr), SINGLE queue read:
// records cached in registers (<=12/thread, static unroll indexing).
__global__ void __launch_bounds__(1024)
k_build(const u64* __restrict__ queue, const int* __restrict__ qtail,
        u64* __restrict__ rs2, unsigned* __restrict__ csr, int N) {
    __shared__ u64 stat[BKT];
    __shared__ int fill[BKT], sc[BKT];
    __shared__ unsigned lcsr[MAXSPAN];
    int t = threadIdx.x, b = blockIdx.x;
    if (t < BKT) stat[t] = 0;
    __syncthreads();
    int cnt = qtail[b];
    size_t q0 = (size_t)b * CAP;
    u64 rec[12];                      // CAP/1024 = 11.75 -> max 12 per thread
#pragma unroll
    for (int k = 0; k < 12; ++k) {
        int i = t + k * 1024;
        rec[k] = (i < cnt) ? queue[q0 + i] : 0;
    }
#pragma unroll
    for (int k = 0; k < 12; ++k) {
        int i = t + k * 1024;
        if (i < cnt) {
            u64 r = rec[k];
            atomicAdd(&stat[(int)((r >> 17) & (BKT - 1))],
                      (1ULL << 32) | (unsigned)(r >> 25));
        }
    }
    __syncthreads();
    int dg = b * BKT + t;
    u64 p = (t < BKT) ? stat[t] : 0;
    int deg = (int)(p >> 32);
    int v = (t < BKT && dg < N) ? ((deg + 1 + 3) & ~3) : 0;   // pad span to x4
    if (t < BKT) sc[t] = v;
    __syncthreads();
    for (int off = 1; off < BKT; off <<= 1) {
        int a = (t >= off && t < BKT) ? sc[t - off] : 0;
        __syncthreads();
        if (t < BKT) sc[t] += a;
        __syncthreads();
    }
    int c0 = b * MAXSPAN;
    if (t < BKT && dg < N) {
        int basel = sc[t] - v;   // exclusive, multiple of 4
        rs2[dg] = (u64)(unsigned)(c0 + basel) | (((u64)(unsigned)(c0 + basel + deg + 1)) << 32);
        fill[t] = basel;
        float mean = ((float)(unsigned)p * (1.0f / 16777216.0f)) / fmaxf((float)deg, 1.0f);
        if (basel + deg < MAXSPAN) lcsr[basel + deg] = (attr_q15(mean) << 17) | (unsigned)dg;
    }
    __syncthreads();
#pragma unroll
    for (int k = 0; k < 12; ++k) {
        int i = t + k * 1024;
        if (i < cnt) {
            u64 r = rec[k];
            int dl = (int)((r >> 17) & (BKT - 1));
            int pos = atomicAdd(&fill[dl], 1);
            float av = (float)(unsigned)(r >> 25) * (1.0f / 16777216.0f);
            if (pos < MAXSPAN) lcsr[pos] = (attr_q15(av) << 17) | (unsigned)(r & 0x1FFFFu);
        }
    }
    __syncthreads();
    int span = sc[BKT - 1];           // total slots used (incl. pads, garbage ok)
    if (span > MAXSPAN) span = MAXSPAN;
    for (int j = t; j < span; j += 1024) csr[c0 + j] = lcsr[j];
}

// ---------- node transform (standalone, layer 2: IN=64, fp16 input) ----------
__global__ void k_node_xf(const __half* __restrict__ h,
                          const _Float16* __restrict__ Wt, const float* __restrict__ bv,
                          __half* __restrict__ xl, __half* __restrict__ xr, int N) {
    __shared__ _Float16 rows[64 * 72];
    xf_block_mfma<64, false>(h, Wt, bv, xl, xr, N, blockIdx.x * 64, rows, threadIdx.x);
}

// ---------- DPP butterfly add: cross-lane sum within 16-lane rows ----------
template<int CTRL>
__device__ __forceinline__ float dpp_add(float c) {
    int t = __builtin_amdgcn_update_dpp(0, __builtin_bit_cast(int, c),
                                        CTRL, 0xF, 0xF, true);
    return c + __builtin_bit_cast(float, t);
}

// ---------- edge micro-step: one 4-edge group (att pre-scaled by log2e) ----------
#define EDGE_GROUP(r, xh, cc)                                                  \
    {                                                                          \
        _Float16 ah = __builtin_bit_cast(_Float16, (unsigned short)((r >> 16) & 0xFFFEu)); \
        half2v aa = {ah, ah};                                                  \
        half2v x01 = {xh.x, xh.y}, x23 = {xh.z, xh.w};                         \
        half2v v01 = aa * We01 + (x01 + xr01);                                 \
        half2v v23 = aa * We23 + (x23 + xr23);                                 \
        half2v s01 = __builtin_elementwise_max(v01, v01 * k02);                \
        half2v s23 = __builtin_elementwise_max(v23, v23 * k02);                \
        cc = __builtin_amdgcn_fdot2(s01, at01, 0.f, false);                    \
        cc = __builtin_amdgcn_fdot2(s23, at23, cc, false);                     \
    }

// ---------- fused edge phase: wave/dst, 16x4 packed fp16, depth-1 pipeline ----
__global__ void k_attn(const __half* __restrict__ xl, const __half* __restrict__ xr,
                       const unsigned* __restrict__ csr, const u64* __restrict__ rs2,
                       const float* __restrict__ We, const float* __restrict__ att,
                       const float* __restrict__ bias,
                       __half* __restrict__ hout, int N) {
    int lane = threadIdx.x & 63;
    int d = (int)(((size_t)blockIdx.x * blockDim.x + threadIdx.x) >> 6);
    if (d >= N) return;
    int eq = lane >> 4;           // which of 4 concurrent edges
    int fl = lane & 15;           // which 4-dim chunk of the 64 dims
    const float LOG2E = 1.44269504088896340736f;
    float4 Wef  = *(const float4*)(We + fl * 4);
    float4 attf = *(const float4*)(att + fl * 4);
    half2v We01 = {(_Float16)Wef.x, (_Float16)Wef.y};
    half2v We23 = {(_Float16)Wef.z, (_Float16)Wef.w};
    half2v at01 = {(_Float16)(attf.x * LOG2E), (_Float16)(attf.y * LOG2E)};
    half2v at23 = {(_Float16)(attf.z * LOG2E), (_Float16)(attf.w * LOG2E)};
    unsigned flo = (unsigned)fl * 4u;
    half4v xrh = *(const half4v*)(xr + (((unsigned)d << 6) | flo));
    half2v xr01 = {xrh.x, xrh.y}, xr23 = {xrh.z, xrh.w};
    const half2v k02 = {(_Float16)0.2f, (_Float16)0.2f};
    u64 rr = rs2[d];
    int e0 = __builtin_amdgcn_readfirstlane((int)(unsigned)rr);
    int e1 = __builtin_amdgcn_readfirstlane((int)(unsigned)(rr >> 32));
    float l = 0.f;
    f32x2 Oa = {0.f, 0.f}, Ob = {0.f, 0.f};
    int e = e0;
    uint4 rv = *(const uint4*)(csr + e + (eq << 2));       // csr padded +256
    half4v xA = *(const half4v*)(xl + (((rv.x & 0x1FFFFu) << 6) | flo));
    half4v xB = *(const half4v*)(xl + (((rv.y & 0x1FFFFu) << 6) | flo));
    half4v xC = *(const half4v*)(xl + (((rv.z & 0x1FFFFu) << 6) | flo));
    half4v xD = *(const half4v*)(xl + (((rv.w & 0x1FFFFu) << 6) | flo));
    for (; e + 16 <= e1; e += 16) {     // 16 edges in flight; e%4==0 (padded spans)
        uint4 rvn = *(const uint4*)(csr + e + 16 + (eq << 2));
        float cA, cB, cC, cD;
        EDGE_GROUP(rv.x, xA, cA);
        EDGE_GROUP(rv.y, xB, cB);
        EDGE_GROUP(rv.z, xC, cC);
        EDGE_GROUP(rv.w, xD, cD);
        half4v nA = *(const half4v*)(xl + (((rvn.x & 0x1FFFFu) << 6) | flo));
        half4v nB = *(const half4v*)(xl + (((rvn.y & 0x1FFFFu) << 6) | flo));
        half4v nC = *(const half4v*)(xl + (((rvn.z & 0x1FFFFu) << 6) | flo));
        half4v nD = *(const half4v*)(xl + (((rvn.w & 0x1FFFFu) << 6) | flo));
        cA = dpp_add<0xB1>(cA);  cB = dpp_add<0xB1>(cB);
        cC = dpp_add<0xB1>(cC);  cD = dpp_add<0xB1>(cD);
        cA = dpp_add<0x4E>(cA);  cB = dpp_add<0x4E>(cB);
        cC = dpp_add<0x4E>(cC);  cD = dpp_add<0x4E>(cD);
        cA = dpp_add<0x141>(cA); cB = dpp_add<0x141>(cB);
        cC = dpp_add<0x141>(cC); cD = dpp_add<0x141>(cD);
        cA = dpp_add<0x140>(cA); cB = dpp_add<0x140>(cB);
        cC = dpp_add<0x140>(cC); cD = dpp_add<0x140>(cD);
        float qA = __builtin_exp2f(cA), qB = __builtin_exp2f(cB);
        float qC = __builtin_exp2f(cC), qD = __builtin_exp2f(cD);
        l += (qA + qB) + (qC + qD);
        f32x2 qA2 = {qA, qA}, qB2 = {qB, qB}, qC2 = {qC, qC}, qD2 = {qD, qD};
        f32x2 xa01 = {(float)xA.x, (float)xA.y}, xa23 = {(float)xA.z, (float)xA.w};
        f32x2 xb01 = {(float)xB.x, (float)xB.y}, xb23 = {(float)xB.z, (float)xB.w};
        f32x2 xc01 = {(float)xC.x, (float)xC.y}, xc23 = {(float)xC.z, (float)xC.w};
        f32x2 xd01 = {(float)xD.x, (float)xD.y}, xd23 = {(float)xD.z, (float)xD.w};
        Oa = __builtin_elementwise_fma(qA2, xa01, Oa);
        Oa = __builtin_elementwise_fma(qB2, xb01, Oa);
        Oa = __builtin_elementwise_fma(qC2, xc01, Oa);
        Oa = __builtin_elementwise_fma(qD2, xd01, Oa);
        Ob = __builtin_elementwise_fma(qA2, xa23, Ob);
        Ob = __builtin_elementwise_fma(qB2, xb23, Ob);
        Ob = __builtin_elementwise_fma(qC2, xc23, Ob);
        Ob = __builtin_elementwise_fma(qD2, xd23, Ob);
        rv = rvn; xA = nA; xB = nB; xC = nC; xD = nD;
    }
    for (; e < e1; e += 4) {            // tail with clamp
        int ee = e + eq;
        bool valid = ee < e1;
        unsigned r = csr[valid ? ee : (e1 - 1)];
        half4v xh = *(const half4v*)(xl + (((r & 0x1FFFFu) << 6) | flo));
        float c;
        EDGE_GROUP(r, xh, c);
        c = dpp_add<0xB1>(c);
        c = dpp_add<0x4E>(c);
        c = dpp_add<0x141>(c);
        c = dpp_add<0x140>(c);
        float q = valid ? __builtin_exp2f(c) : 0.f;
        l += q;
        Oa.x = fmaf(q, (float)xh.x, Oa.x);
        Oa.y = fmaf(q, (float)xh.y, Oa.y);
        Ob.x = fmaf(q, (float)xh.z, Ob.x);
        Ob.y = fmaf(q, (float)xh.w, Ob.y);
    }
#pragma unroll
    for (int mm = 16; mm <= 32; mm <<= 1) {
        l    += __shfl_xor(l, mm, 64);
        Oa.x += __shfl_xor(Oa.x, mm, 64);
        Oa.y += __shfl_xor(Oa.y, mm, 64);
        Ob.x += __shfl_xor(Ob.x, mm, 64);
        Ob.y += __shfl_xor(Ob.y, mm, 64);
    }
    if (eq == 0) {
        float inv = 1.0f / (l + 1e-16f);
        float4 b4 = *(const float4*)(bias + fl * 4);
        float4 res;
        res.x = fmaf(Oa.x, inv, b4.x);
        res.y = fmaf(Oa.y, inv, b4.y);
        res.z = fmaf(Ob.x, inv, b4.z);
        res.w = fmaf(Ob.y, inv, b4.w);
        res.x = res.x > 0.f ? res.x : __expf(res.x) - 1.f;
        res.y = res.y > 0.f ? res.y : __expf(res.y) - 1.f;
        res.z = res.z > 0.f ? res.z : __expf(res.z) - 1.f;
        res.w = res.w > 0.f ? res.w : __expf(res.w) - 1.f;
        half4v rh = {(_Float16)res.x, (_Float16)res.y, (_Float16)res.z, (_Float16)res.w};
        *(half4v*)(hout + (((size_t)d << 6) | flo)) = rh;
    }
}

// ---------- pool (+ fused head), fp16 h, 16 nodes/wave + block-LDS slots ----
// Release via s_waitcnt vmcnt(0) (atomics are device-scope); acquire
// __threadfence() only in the single last-done block (v17 fence fix).
__global__ void k_pool_head(const __half* __restrict__ h, const int* __restrict__ batch,
                            float* __restrict__ pooled, float* __restrict__ gcnt,
                            int N, int* __restrict__ done,
                            const float* __restrict__ W1, const float* __restrict__ b1,
                            const float* __restrict__ gam, const float* __restrict__ bet,
                            const float* __restrict__ mu, const float* __restrict__ var,
                            const float* __restrict__ W3, const float* __restrict__ b3,
                            float* __restrict__ out, int G) {
    __shared__ float sacc[4][65];     // 4 group slots x (64 dims + count)
    int tid = threadIdx.x;
    int lane = tid & 63, w = tid >> 6;
    int blockBegin = blockIdx.x * 64;
    for (int i = tid; i < 4 * 65; i += 256) (&sacc[0][0])[i] = 0.f;
    __syncthreads();
    if (blockBegin < N) {
        int gfirst = batch[blockBegin];
        int begin = blockBegin + w * 16;
        if (begin < N) {
            int bidx = begin + (lane & 15);
            int bval = batch[bidx < N ? bidx : (N - 1)];
            float hv[16];                 // 16 regs: loads genuinely in flight
#pragma unroll
            for (int j = 0; j < 16; ++j) {
                int n = begin + j;
                hv[j] = (n < N) ? __half2float(h[((size_t)n << 6) + lane]) : 0.f;
            }
            int g = __shfl(bval, 0, 64);
            float acc = 0.f, cnt = 0.f;
#pragma unroll
            for (int j = 0; j < 16; ++j) {
                if (begin + j < N) {          // wave-uniform
                    int gn = __shfl(bval, j, 64);
                    if (gn != g) {
                        int slot = g - gfirst;
                        if (slot < 4) {
                            atomicAdd(&sacc[slot][lane], acc);
                            if (lane == 0) atomicAdd(&sacc[slot][64], cnt);
                        } else {
                            atomicAdd(&pooled[((size_t)g << 6) + lane], acc);
                            if (lane == 0) atomicAdd(&gcnt[g], cnt);
                        }
                        g = gn; acc = 0.f; cnt = 0.f;
                    }
                    acc += hv[j];
                    cnt += 1.f;
                }
            }
            int slot = g - gfirst;
            if (slot < 4) {
                atomicAdd(&sacc[slot][lane], acc);
                if (lane == 0) atomicAdd(&sacc[slot][64], cnt);
            } else {
                atomicAdd(&pooled[((size_t)g << 6) + lane], acc);
                if (lane == 0) atomicAdd(&gcnt[g], cnt);
            }
        }
        __syncthreads();
        // flush: wave w owns slot w
        float c = sacc[w][64];
        if (c != 0.f) {
            int g = gfirst + w;
            atomicAdd(&pooled[((size_t)g << 6) + lane], sacc[w][lane]);
            if (lane == 0) atomicAdd(&gcnt[g], c);
        }
    }
    // release: drain our device-scope atomics. NOT __threadfence() (= full-L2
    // writeback per wave on non-coherent per-XCD L2s -> was the pool floor).
    asm volatile("s_waitcnt vmcnt(0)" ::: "memory");
    __syncthreads();
    __shared__ int lastFlag;
    if (tid == 0) lastFlag = (atomicAdd(done, 1) == (int)gridDim.x - 1);
    __syncthreads();
    if (lastFlag && tid < G) {
        __threadfence();   // acquire: invalidate stale local cache lines (1 block)
        int g = tid;
        float inv = 1.0f / fmaxf(gcnt[g], 1.0f);
        float pr[64];
        for (int k = 0; k < 64; ++k) pr[k] = pooled[((size_t)g << 6) + k] * inv;
        float o = b3[0];
        for (int j = 0; j < 32; ++j) {
            float z = b1[j];
            for (int k = 0; k < 64; ++k) z += pr[k] * W1[k * 32 + j];
            z = fmaxf(z, 0.f);
            z = (z - mu[j]) / sqrtf(var[j] + 1e-5f) * gam[j] + bet[j];
            o += z * W3[j];
        }
        out[g] = o;
    }
}

// ---------- launch ----------
extern "C" void kernel_launch(void* const* d_in, const int* in_sizes, int n_in,
                              void* d_out, int out_size, void* d_ws, size_t ws_size,
                              hipStream_t stream) {
    const float* x    = (const float*)d_in[0];
    const int*   ei   = (const int*)d_in[1];
    const float* ea   = (const float*)d_in[2];
    const int*   batch= (const int*)d_in[3];
    const float* Wl1  = (const float*)d_in[4];
    const float* bl1  = (const float*)d_in[5];
    const float* Wr1  = (const float*)d_in[6];
    const float* br1  = (const float*)d_in[7];
    const float* We1  = (const float*)d_in[8];
    const float* att1 = (const float*)d_in[9];
    const float* bi1  = (const float*)d_in[10];
    const float* Wl2  = (const float*)d_in[11];
    const float* bl2  = (const float*)d_in[12];
    const float* Wr2  = (const float*)d_in[13];
    const float* br2  = (const float*)d_in[14];
    const float* We2  = (const float*)d_in[15];
    const float* att2 = (const float*)d_in[16];
    const float* bi2  = (const float*)d_in[17];
    const float* Wf1  = (const float*)d_in[18];
    const float* bf1  = (const float*)d_in[19];
    const float* gam  = (const float*)d_in[20];
    const float* bet  = (const float*)d_in[21];
    const float* mu   = (const float*)d_in[22];
    const float* var  = (const float*)d_in[23];
    const float* Wf3  = (const float*)d_in[24];
    const float* bf3  = (const float*)d_in[25];

    const int N    = in_sizes[3];          // 50000
    const int E    = in_sizes[2];          // 1600000
    const int INd  = in_sizes[0] / N;      // 128
    const int ld1  = (INd == 128) ? 7 : 6;
    const int G    = out_size;             // 64
    const int NB   = (N + BKT - 1) / BKT;  // 256-dst buckets (196)

    // workspace carve-up (256B aligned)
    char* w = (char*)d_ws;
    auto carve = [&](size_t bytes) { char* p = w; w += (bytes + 255) & ~(size_t)255; return p; };
    __half*   xl       = (__half*)  carve((size_t)N * 64 * 2);
    __half*   xr       = (__half*)  carve((size_t)N * 64 * 2);
    __half*   hbuf     = (__half*)  carve((size_t)N * 64 * 2);   // fp16
    unsigned* csr      = (unsigned*)carve(((size_t)NB * MAXSPAN + 256) * 4);  // +prefetch pad
    u64*      queue    = (u64*)     carve((size_t)NB * CAP * 8);
    u64*      rs2      = (u64*)     carve((size_t)N * 8);
    // zeroed region: qtail + pooled + gcnt + done (contiguous, single memset)
    char*     z0       = w;
    int*      qtail    = (int*)     carve((size_t)(NB + 1) * 4);
    float*    pooled   = (float*)   carve((size_t)G * 64 * 4);
    float*    gcnt     = (float*)   carve((size_t)G * 4);
    int*      done     = (int*)     carve(256);
    size_t    zbytes   = (size_t)(w - z0);
    _Float16* Wt1      = (_Float16*)carve((size_t)128 * 128 * 2);
    float*    bv1      = (float*)   carve(128 * 4);
    _Float16* Wt2      = (_Float16*)carve((size_t)128 * 64 * 2);
    float*    bv2      = (float*)   carve(128 * 4);

    const int TB = 256;
    const int nbXF = (N + 63) / 64;              // node-transform blocks
    const int attnBlocks = (N + 3) / 4;          // wave per dst, 4 waves/block
    const int nbPart = (E + PEPB - 1) / PEPB;    // 391 partition blocks
    const int nbPool = (N + 63) / 64;            // 64 nodes per pool block

    // ---- zero counters (single memset) ----
    hipMemsetAsync(z0, 0, zbytes, stream);

    // ---- weight prep (fp16, transposed, fused bias) ----
    k_prep_w<<<32, TB, 0, stream>>>(Wl1, bl1, Wr1, br1, Wl2, bl2, Wr2, br2,
                                    Wt1, bv1, Wt2, bv2, ld1);

    // ---- fused: layer-1 node transform (MFMA) || edge partition ----
    if (INd == 128)
        k_xf1_part<128><<<nbXF + nbPart, TB, 0, stream>>>(x, Wt1, bv1, xl, xr, N, nbXF,
                                                          ei, ea, qtail, queue, E);
    else
        k_xf1_part<64><<<nbXF + nbPart, TB, 0, stream>>>(x, Wt1, bv1, xl, xr, N, nbXF,
                                                         ei, ea, qtail, queue, E);
    k_build<<<NB, 1024, 0, stream>>>(queue, qtail, rs2, csr, N);

    // ---- layer 1 edge phase ----
    k_attn<<<attnBlocks, TB, 0, stream>>>(xl, xr, csr, rs2, We1, att1, bi1, hbuf, N);

    // ---- layer 2 ----
    k_node_xf<<<nbXF, TB, 0, stream>>>(hbuf, Wt2, bv2, xl, xr, N);
    k_attn<<<attnBlocks, TB, 0, stream>>>(xl, xr, csr, rs2, We2, att2, bi2, hbuf, N);

    // ---- pool + head (fused) ----
    k_pool_head<<<nbPool, TB, 0, stream>>>(
        hbuf, batch, pooled, gcnt, N, done,
        Wf1, bf1, gam, bet, mu, var, Wf3, bf3, (float*)d_out, G);
}